// Round 8
// baseline (142.807 us; speedup 1.0000x reference)
//
#include <hip/hip_runtime.h>

typedef float v2f __attribute__((ext_vector_type(2)));

namespace {

constexpr int Tn = 1000, Fn = 22, Hn = 10, Cn = 4;
constexpr int CHF  = 32 * Fn;     // 704 floats per 32-step x chunk
constexpr int HB   = 2 * CHF;     // h-zone float offset (1408)
constexpr int LDSF = HB + 128;    // 4 h-rows * 16 + 64-float dump

__device__ __forceinline__ v2f mk2(float a, float b){ v2f r; r.x=a; r.y=b; return r; }
__device__ __forceinline__ v2f fma2(v2f a, v2f b, v2f c){ return __builtin_elementwise_fma(a,b,c); }
__device__ __forceinline__ float rlane(float v, int l){
    return __uint_as_float(__builtin_amdgcn_readlane(__float_as_uint(v), l));
}
__device__ __forceinline__ void gld_lds4(const float* g, float* l){
    __builtin_amdgcn_global_load_lds(
        (const __attribute__((address_space(1))) unsigned int*)g,
        (__attribute__((address_space(3))) unsigned int*)l, 4, 0, 0);
}
__device__ __forceinline__ void sfence(){ __builtin_amdgcn_sched_barrier(0); }

// h-zone rows (float offsets from HB): h1r0 @0, h1r1 @16, h2r0 @32, h2r1 @48, dump @64.
// Step s (E = even) consumes {h1r1, h2r0}, writes {h1r0, h2r1}; O steps the reverse.
// => every step's reads target exactly the rows the SAME step just wrote (issued
// back-to-back, LDS pipe order guarantees the dependency), and rows read next
// step were written this step.

__global__ __launch_bounds__(64, 1) void rnn_lds(
    const float* __restrict__ x,
    const float* __restrict__ w_ih0, const float* __restrict__ w_hh0,
    const float* __restrict__ b_ih0, const float* __restrict__ b_hh0,
    const float* __restrict__ w_ih1, const float* __restrict__ w_hh1,
    const float* __restrict__ b_ih1, const float* __restrict__ b_hh1,
    const float* __restrict__ w_lin, const float* __restrict__ b_lin,
    float* __restrict__ out)
{
    __shared__ __align__(16) float lds[LDSF];

    const int lane = threadIdx.x;       // one wave per block, one batch per wave
    const int b    = blockIdx.x;
    const int half = lane >> 5;         // 0: even-step x, 1: odd-step x
    const int l31  = lane & 31;
    const int jz   = (l31 < Hn) ? l31 : 0;                      // h1 / z row
    const int j2   = (l31 >= 16 && l31 < 16 + Hn) ? (l31 - 16) : 0;  // h2 row
    const bool isH1 = (l31 < 16);

    // ---- packed per-lane weights ----
    v2f wih0p[11], whh0p[5], wih1p[5], whh1p[5];
    #pragma unroll
    for (int p = 0; p < 11; ++p)
        wih0p[p] = mk2(w_ih0[jz*Fn + 2*p], w_ih0[jz*Fn + 2*p + 1]);
    #pragma unroll
    for (int k = 0; k < 5; ++k) {
        whh0p[k] = mk2(w_hh0[jz*Hn + 2*k], w_hh0[jz*Hn + 2*k + 1]);
        wih1p[k] = mk2(w_ih1[j2*Hn + 2*k], w_ih1[j2*Hn + 2*k + 1]);
        whh1p[k] = mk2(w_hh1[j2*Hn + 2*k], w_hh1[j2*Hn + 2*k + 1]);
    }
    const v2f bz2 = mk2(b_ih0[jz] + b_hh0[jz], 0.f);   // bias1 folded into z
    const v2f b2p = mk2(b_ih1[j2] + b_hh1[j2], 0.f);   // bias2 folded into a2

    // ---- per-lane h write pointers (junk lanes -> distinct dump slots) ----
    const int dmp = HB + 64 + lane;
    float* pwE  = lds + ((lane < 10) ? HB + lane
                        : (lane >= 16 && lane < 26) ? HB + 48 + (lane - 16) : dmp);
    float* pwO  = lds + ((lane >= 32 && lane < 42) ? HB + 16 + (lane - 32)
                        : (lane >= 48 && lane < 58) ? HB + 32 + (lane - 48) : dmp);
    float* pwE0 = lds + ((lane < 10) ? HB + lane : dmp);   // step 0: keep h2r1 zero

    const float* __restrict__ xrow = x + (size_t)b * (Tn * Fn);

    auto stage = [&](int c){                       // x chunk c -> slot c&1 (r6 proven)
        float* dst = lds + (c & 1) * CHF;
        const float* src = xrow + c * CHF;
        if (c < 31) {
            #pragma unroll
            for (int k = 0; k < 11; ++k) gld_lds4(src + k*64 + lane, dst + k*64);
        } else {                                   // chunk 31: 176 valid floats
            gld_lds4(src + lane, dst);
            gld_lds4(src + 64 + lane, dst + 64);
            if (lane < 48) gld_lds4(src + 128 + lane, dst + 128);
        }
    };

    // zero the h-zone (rings + dump); same-wave program order covers the reads below
    lds[HB + lane] = 0.f;
    lds[HB + 64 + lane] = 0.f;

    stage(0); stage(1);

    // direct global x: xv1 <- pair 0, xv0 <- pair 1 (per half)
    v2f xv0[11], xv1[11];
    {
        const float* r01 = xrow + half * Fn;
        #pragma unroll
        for (int p = 0; p < 11; ++p) xv1[p] = *(const v2f*)(r01 + 2*p);
        const float* r23 = xrow + (2 + half) * Fn;
        #pragma unroll
        for (int p = 0; p < 11; ++p) xv0[p] = *(const v2f*)(r23 + 2*p);
    }

    auto zc = [&](const v2f* xp)->float{           // z-pair: 11 pk-FMA chain
        v2f z = fma2(xp[0], wih0p[0], bz2);
        #pragma unroll
        for (int p = 1; p < 11; ++p) z = fma2(xp[p], wih0p[p], z);
        return z.x + z.y;
    };
    auto pairptr = [&](int P)->const float*{       // x pair P, this lane's half
        return lds + ((P >> 4) & 1) * CHF + (P & 15) * 44 + half * 22;
    };
    auto loadxv = [&](v2f* dst, const float* rp){
        #pragma unroll
        for (int p = 0; p < 11; ++p) dst[p] = *(const v2f*)(rp + 2*p);
        sfence();
    };

    // h vector register sets (double-buffered across steps)
    v2f h1a[5], h2a[5], h1b[5], h2b[5];
    auto readE = [&](v2f* d1, v2f* d2){            // vecs for an E step: h1r1, h2r0
        #pragma unroll
        for (int k = 0; k < 5; ++k) d1[k] = *(const v2f*)&lds[HB + 16 + 2*k];
        #pragma unroll
        for (int k = 0; k < 5; ++k) d2[k] = *(const v2f*)&lds[HB + 32 + 2*k];
        sfence();
    };
    auto readO = [&](v2f* d1, v2f* d2){            // vecs for an O step: h1r0, h2r1
        #pragma unroll
        for (int k = 0; k < 5; ++k) d1[k] = *(const v2f*)&lds[HB + 0 + 2*k];
        #pragma unroll
        for (int k = 0; k < 5; ++k) d2[k] = *(const v2f*)&lds[HB + 48 + 2*k];
        sfence();
    };

    // one step: L1(s) in h1-lanes, L2(s-1) in h2-lanes, all-pk dots
    auto core = [&](float z, const v2f* c1, const v2f* c2)->float{
        v2f A = c1[0] * whh0p[0];
        A = fma2(c1[1], whh0p[1], A);
        A = fma2(c1[2], whh0p[2], A);
        A = fma2(c1[3], whh0p[3], A);
        A = fma2(c1[4], whh0p[4], A);
        v2f B = fma2(c1[0], wih1p[0], b2p);
        B = fma2(c1[1], wih1p[1], B);
        B = fma2(c1[2], wih1p[2], B);
        B = fma2(c1[3], wih1p[3], B);
        B = fma2(c1[4], wih1p[4], B);
        B = fma2(c2[0], whh1p[0], B);
        B = fma2(c2[1], whh1p[1], B);
        B = fma2(c2[2], whh1p[2], B);
        B = fma2(c2[3], whh1p[3], B);
        B = fma2(c2[4], whh1p[4], B);
        const float a1s = (A.x + A.y) + z;
        const float a2s = B.x + B.y;
        return fmaxf(isH1 ? a1s : a2s, 0.f);
    };

    float zA, zB;
    asm volatile("s_waitcnt vmcnt(0)" ::: "memory");   // chunks 0,1 + direct x ready
    zA = zc(xv1);                                      // z(0)/z(1)

    readE(h1a, h2a);   // step-0 vectors (all zeros)

    // 4 steps: E,O,E,O = s = 4m .. 4m+3
    auto MACRO = [&](int m, float* pwEf, bool ld0, bool ld1, bool zA1){
        float hn = core(zA, h1a, h2a);      // s = 4m   (E)
        *pwEf = hn;
        readO(h1b, h2b);
        if (ld0) loadxv(xv1, pairptr(2*m + 2));
        hn = core(zA, h1b, h2b);            // s = 4m+1 (O)
        *pwO = hn;
        readE(h1a, h2a);
        zB = zc(xv0);
        hn = core(zB, h1a, h2a);            // s = 4m+2 (E)
        *pwE = hn;
        readO(h1b, h2b);
        if (ld1) loadxv(xv0, pairptr(2*m + 3));
        hn = core(zB, h1b, h2b);            // s = 4m+3 (O)
        *pwO = hn;
        readE(h1a, h2a);
        if (zA1) zA = zc(xv1);
    };

    MACRO(0, pwE0, true, true, true);       // step 0 keeps h2r1 == 0 (h2(-1))
    #pragma unroll 1
    for (int m = 1; m < 249; ++m) {
        if ((m & 7) == 7) {                 // r6-proven DMA cadence
            asm volatile("s_waitcnt vmcnt(0)" ::: "memory");
            const int c = (m >> 3) + 2;
            if (c <= 31) stage(c);
        }
        MACRO(m, pwE, true, true, true);
    }
    MACRO(249, pwE, false, false, false);   // t = 996..999

    // ---- epilogue: set a = {h1(999), h2(998)} -> h2(999) in h2-lanes ----
    float S2[Hn];
    {
        v2f B = fma2(h1a[0], wih1p[0], b2p);
        B = fma2(h1a[1], wih1p[1], B);
        B = fma2(h1a[2], wih1p[2], B);
        B = fma2(h1a[3], wih1p[3], B);
        B = fma2(h1a[4], wih1p[4], B);
        B = fma2(h2a[0], whh1p[0], B);
        B = fma2(h2a[1], whh1p[1], B);
        B = fma2(h2a[2], whh1p[2], B);
        B = fma2(h2a[3], whh1p[3], B);
        B = fma2(h2a[4], whh1p[4], B);
        const float h2f = fmaxf(B.x + B.y, 0.f);
        #pragma unroll
        for (int k = 0; k < Hn; ++k) S2[k] = rlane(h2f, 16 + k);  // epilogue-only
    }

    // ---- head: out[b,:] = h2(999) @ w_lin.T + b_lin ----
    const int jc = (lane < Cn) ? lane : 0;
    float o = b_lin[jc];
    #pragma unroll
    for (int k = 0; k < Hn; ++k) o = fmaf(S2[k], w_lin[jc*Hn + k], o);
    if (lane < Cn) out[b * Cn + lane] = o;
}

} // namespace

extern "C" void kernel_launch(void* const* d_in, const int* in_sizes, int n_in,
                              void* d_out, int out_size, void* d_ws, size_t ws_size,
                              hipStream_t stream) {
    const float* x     = (const float*)d_in[0];
    const float* w_ih0 = (const float*)d_in[1];
    const float* w_hh0 = (const float*)d_in[2];
    const float* b_ih0 = (const float*)d_in[3];
    const float* b_hh0 = (const float*)d_in[4];
    const float* w_ih1 = (const float*)d_in[5];
    const float* w_hh1 = (const float*)d_in[6];
    const float* b_ih1 = (const float*)d_in[7];
    const float* b_hh1 = (const float*)d_in[8];
    const float* w_lin = (const float*)d_in[9];
    const float* b_lin = (const float*)d_in[10];
    float* out = (float*)d_out;

    // one batch per 64-thread block: 1024 waves, 1 per SIMD
    rnn_lds<<<dim3(1024), dim3(64), 0, stream>>>(
        x, w_ih0, w_hh0, b_ih0, b_hh0,
        w_ih1, w_hh1, b_ih1, b_hh1, w_lin, b_lin, out);
}

// Round 9
// 103.960 us; speedup vs baseline: 1.3737x; 1.3737x over previous
//
#include <hip/hip_runtime.h>

typedef float v2f __attribute__((ext_vector_type(2)));
typedef _Float16 h2f __attribute__((ext_vector_type(2)));

namespace {

constexpr int Tn = 1000, Fn = 22, Hn = 10, Cn = 4;
constexpr int CHF = 32 * Fn;          // 704 floats per 32-step x chunk

__device__ __forceinline__ v2f mk2(float a, float b){ v2f r; r.x=a; r.y=b; return r; }
__device__ __forceinline__ v2f fma2(v2f a, v2f b, v2f c){ return __builtin_elementwise_fma(a,b,c); }
__device__ __forceinline__ float rlanef(float v, int l){
    return __uint_as_float(__builtin_amdgcn_readlane(__float_as_uint(v), l));
}
__device__ __forceinline__ unsigned rlaneu(unsigned v, int l){
    return (unsigned)__builtin_amdgcn_readlane((int)v, l);
}
__device__ __forceinline__ void gld_lds4(const float* g, float* l){
    __builtin_amdgcn_global_load_lds(
        (const __attribute__((address_space(1))) unsigned int*)g,
        (__attribute__((address_space(3))) unsigned int*)l, 4, 0, 0);
}
__device__ __forceinline__ void sfence(){ __builtin_amdgcn_sched_barrier(0); }
__device__ __forceinline__ h2f u2h(unsigned u){ return __builtin_bit_cast(h2f, u); }

__global__ __launch_bounds__(64, 1) void rnn_dot16(
    const float* __restrict__ x,
    const float* __restrict__ w_ih0, const float* __restrict__ w_hh0,
    const float* __restrict__ b_ih0, const float* __restrict__ b_hh0,
    const float* __restrict__ w_ih1, const float* __restrict__ w_hh1,
    const float* __restrict__ b_ih1, const float* __restrict__ b_hh1,
    const float* __restrict__ w_lin, const float* __restrict__ b_lin,
    float* __restrict__ out)
{
    __shared__ __align__(16) float ch[2][CHF];   // x chunk c -> ch[c&1]

    const int lane = threadIdx.x;     // one wave per block, one batch per wave
    const int b    = blockIdx.x;
    const int half = lane >> 5;       // 0: even-step x, 1: odd-step x
    const int l31  = lane & 31;

    const int jz = (l31 < Hn) ? l31 : 0;                 // z / L1 row
    const bool isl2 = (l31 >= 16) && (l31 < 16 + Hn);
    const int j2 = isl2 ? (l31 - 16) : 0;

    // ---- per-lane weights: L1-side lanes get w_hh0; L2-side w_ih1 + w_hh1 ----
    // f16 pairs for the state dots (f32 accumulate via v_dot2_f32_f16)
    const float* pwa = (l31 < 16) ? (w_hh0 + jz * Hn) : (w_ih1 + j2 * Hn);
    h2f waH[5], wbH[5];
    #pragma unroll
    for (int k = 0; k < 5; ++k) {
        h2f t; t.x = (_Float16)pwa[2*k]; t.y = (_Float16)pwa[2*k+1];
        waH[k] = t;
        h2f u; u.x = isl2 ? (_Float16)w_hh1[j2*Hn + 2*k]     : (_Float16)0.f;
               u.y = isl2 ? (_Float16)w_hh1[j2*Hn + 2*k + 1] : (_Float16)0.f;
        wbH[k] = u;
    }
    v2f wih0p[11];                                        // z weights stay f32
    #pragma unroll
    for (int p = 0; p < 11; ++p)
        wih0p[p] = mk2(w_ih0[jz*Fn + 2*p], w_ih0[jz*Fn + 2*p + 1]);
    const float bias1  = b_ih0[jz] + b_hh0[jz];
    const float bias2v = b_ih1[j2] + b_hh1[j2];
    const v2f bz2 = mk2(bias1, 0.f);

    const bool mL = (lane < Hn);                     // z-holders, even steps
    const bool mU = (lane >= 32) && (lane < 32+Hn);  // z-holders, odd steps

    const float* __restrict__ xrow = x + (size_t)b * (Tn * Fn);

    // ---- DMA staging: chunk c (32 steps) -> ch[c&1] (r6-proven) ----
    auto stage = [&](int c) {
        float* dst = ch[c & 1];
        const float* src = xrow + c * CHF;
        if (c < 31) {
            #pragma unroll
            for (int k = 0; k < 11; ++k) gld_lds4(src + k*64 + lane, dst + k*64);
        } else {                          // chunk 31: 176 valid floats
            gld_lds4(src + lane, dst);
            gld_lds4(src + 64 + lane, dst + 64);
            if (lane < 48) gld_lds4(src + 128 + lane, dst + 128);
        }
    };
    stage(0); stage(1);

    // ---- direct global x for pairs 0,1 (lower half x(2p), upper x(2p+1)) ----
    v2f xd[11], xv0[11], xv1[11];
    {
        const float* r01 = xrow + half * Fn;
        #pragma unroll
        for (int p = 0; p < 11; ++p) xd[p] = *(const v2f*)(r01 + 2*p);
        const float* r23 = xrow + (2 + half) * Fn;
        #pragma unroll
        for (int p = 0; p < 11; ++p) xv0[p] = *(const v2f*)(r23 + 2*p);
    }

    auto zc = [&](const v2f* xp) -> float {          // z-pair: 11 pk-FMA chain (f32)
        v2f z = fma2(xp[0], wih0p[0], bz2);
        #pragma unroll
        for (int p = 1; p < 11; ++p) z = fma2(xp[p], wih0p[p], z);
        return z.x + z.y;
    };
    auto pairptr = [&](int P) -> const float* {      // x pair P, this lane's half
        return &ch[(P >> 4) & 1][(P & 15) * 44 + half * 22];
    };
    auto loadxv = [&](v2f* dst, const float* rp) {
        #pragma unroll
        for (int p = 0; p < 11; ++p) dst[p] = *(const v2f*)(rp + 2*p);
        sfence();
    };

    // h-state as packed f16 pairs in SGPRs: S1u[k]=(h1[2k],h1[2k+1]), S2u likewise
    unsigned S1u[5], S2u[5];
    #pragma unroll
    for (int k = 0; k < 5; ++k) { S1u[k] = 0u; S2u[k] = 0u; }

    float zA, zB;
    asm volatile("s_waitcnt vmcnt(0)" ::: "memory");  // chunks 0,1 + direct x ready
    zA = zc(xd);     // z(0) on lanes 0-9, z(1) on lanes 32-41

    // one step: L1(t) & L2(t-1) in one uniform stream, f16-pair state
    auto dostep = [&](bool up, float z, bool commit2) {
        const float base = (up ? mU : mL) ? z : bias2v;
        float aA = base, aB = 0.f;
        #pragma unroll
        for (int k = 0; k < 5; ++k)
            aA = __builtin_amdgcn_fdot2(u2h(S1u[k]), waH[k], aA, false);
        #pragma unroll
        for (int k = 0; k < 5; ++k)
            aB = __builtin_amdgcn_fdot2(u2h(S2u[k]), wbH[k], aB, false);
        const float hn = fmaxf(aA + aB, 0.f);
        // pair-pack: neighbor's hn via DPP quad-perm [1,0,3,2], then pkrtz
        const float nb = __uint_as_float((unsigned)__builtin_amdgcn_mov_dpp(
                             (int)__float_as_uint(hn), 0xB1, 0xF, 0xF, false));
        const unsigned pk = __builtin_bit_cast(unsigned,
                             __builtin_amdgcn_cvt_pkrtz(hn, nb));
        const int s1b = up ? 32 : 0;          // h1 pairs on even lanes s1b+{0,2,4,6,8}
        #pragma unroll
        for (int k = 0; k < 5; ++k) S1u[k] = rlaneu(pk, s1b + 2*k);
        if (commit2) {                        // h2 pairs on even lanes s1b+16+{0..8}
            #pragma unroll
            for (int k = 0; k < 5; ++k) S2u[k] = rlaneu(pk, s1b + 16 + 2*k);
        }
    };

    // macro = 4 steps t=4m..4m+3: {L0(zA), U0(zA), L1(zB), U1(zB)}  (r6-proven)
    auto MACRO = [&](int m, bool s2_0, bool ld0, bool ld1, bool z1) {
        if (ld0) loadxv(xv1, pairptr(2*m + 2));
        dostep(false, zA, s2_0);
        zB = zc(xv0);
        dostep(true, zA, true);
        if (ld1) loadxv(xv0, pairptr(2*m + 3));
        dostep(false, zB, true);
        if (z1) zA = zc(xv1);
        dostep(true, zB, true);
    };

    // m=0: no S2 commit at t=0 (h2(-1) stays 0 for t=1)
    MACRO(0, false, true, true, true);

    #pragma unroll 1
    for (int m = 1; m < 249; ++m) {
        if ((m & 7) == 7) {                   // r6-proven DMA cadence
            asm volatile("s_waitcnt vmcnt(0)" ::: "memory");
            const int c = (m >> 3) + 2;
            if (c <= 31) stage(c);
        }
        MACRO(m, true, true, true, true);
    }
    MACRO(249, true, false, false, false);    // t = 996..999

    // ---- epilogue: h2(999) = relu(b2 + W_ih1 h1(999) + W_hh1 h2(998)) ----
    float S2f[Hn];
    {
        float aA = bias2v, aB = 0.f;
        #pragma unroll
        for (int k = 0; k < 5; ++k)
            aA = __builtin_amdgcn_fdot2(u2h(S1u[k]), waH[k], aA, false);
        #pragma unroll
        for (int k = 0; k < 5; ++k)
            aB = __builtin_amdgcn_fdot2(u2h(S2u[k]), wbH[k], aB, false);
        const float h2f_ = fmaxf(aA + aB, 0.f);     // valid on lanes 16-25
        #pragma unroll
        for (int k = 0; k < Hn; ++k) S2f[k] = rlanef(h2f_, 16 + k);
    }

    // ---- head: out[b,:] = h2(999) @ w_lin.T + b_lin (f32) ----
    const int jc = (lane < Cn) ? lane : 0;
    float o = b_lin[jc];
    #pragma unroll
    for (int k = 0; k < Hn; ++k) o = fmaf(S2f[k], w_lin[jc*Hn + k], o);
    if (lane < Cn) out[b * Cn + lane] = o;
}

} // namespace

extern "C" void kernel_launch(void* const* d_in, const int* in_sizes, int n_in,
                              void* d_out, int out_size, void* d_ws, size_t ws_size,
                              hipStream_t stream) {
    const float* x     = (const float*)d_in[0];
    const float* w_ih0 = (const float*)d_in[1];
    const float* w_hh0 = (const float*)d_in[2];
    const float* b_ih0 = (const float*)d_in[3];
    const float* b_hh0 = (const float*)d_in[4];
    const float* w_ih1 = (const float*)d_in[5];
    const float* w_hh1 = (const float*)d_in[6];
    const float* b_ih1 = (const float*)d_in[7];
    const float* b_hh1 = (const float*)d_in[8];
    const float* w_lin = (const float*)d_in[9];
    const float* b_lin = (const float*)d_in[10];
    float* out = (float*)d_out;

    // one batch per 64-thread block: 1024 waves, 1 per SIMD
    rnn_dot16<<<dim3(1024), dim3(64), 0, stream>>>(
        x, w_ih0, w_hh0, b_ih0, b_hh0,
        w_ih1, w_hh1, b_ih1, b_hh1, w_lin, b_lin, out);
}